// Round 10
// baseline (187.212 us; speedup 1.0000x reference)
//
#include <hip/hip_runtime.h>

// Wav2Vec2 Gumbel VQ — round 10: decorrelated small blocks. Same per-wave code
// as r9 (VGPR-safe, sched_barrier ping-pong GEMM), but 256-thr/4-wave blocks,
// one group per block (grid 4096), 4 blocks/CU -> each SIMD gets 4 waves from
// 4 DIFFERENT blocks = 4 independent stall streams (r9 had 2, barrier-locked).

#define GG   2
#define KK   320
#define NN   65536
#define DD   512
#define DPG  128
#define EPSL 1e-7f
#define NCPY 8

typedef __attribute__((ext_vector_type(8))) short bf16x8;   // 8 x bf16
typedef __attribute__((ext_vector_type(4))) float f32x4;

static __device__ __forceinline__ unsigned short f2bf_rne(float f) {
    unsigned u = __float_as_uint(f);
    u += 0x7FFFu + ((u >> 16) & 1u);
    return (unsigned short)(u >> 16);
}

static __device__ __forceinline__ bf16x8 pack8_rne(float4 v0, float4 v1) {
    union { unsigned short s[8]; bf16x8 b; } u;
    u.s[0] = f2bf_rne(v0.x); u.s[1] = f2bf_rne(v0.y);
    u.s[2] = f2bf_rne(v0.z); u.s[3] = f2bf_rne(v0.w);
    u.s[4] = f2bf_rne(v1.x); u.s[5] = f2bf_rne(v1.y);
    u.s[6] = f2bf_rne(v1.z); u.s[7] = f2bf_rne(v1.w);
    return u.b;
}

// ---------- prep: W (640x512 f32) -> fragment-ordered bf16 (RNE) ----------
// w = ct*16 + t; element (w*512 + l*8 + j) = W[col=16ct+(l&15)][k=32t+8(l>>4)+j]
__global__ __launch_bounds__(256) void prep_w(const float* __restrict__ W,
                                              short* __restrict__ Wf) {
    int gt = blockIdx.x * 256 + threadIdx.x;          // 40960 threads
    int w  = gt >> 6, l = gt & 63;
    int col = 16 * (w >> 4) + (l & 15);
    int k0  = 32 * (w & 15) + 8 * (l >> 4);
    const float* src = W + (size_t)col * DD + k0;
    float4 v0 = *(const float4*)(src);
    float4 v1 = *(const float4*)(src + 4);
    *(bf16x8*)(Wf + (size_t)w * 512 + (size_t)l * 8) = pack8_rne(v0, v1);
}

// ---------- main fused kernel ----------
// grid: 4096 blocks = 2048 row-tiles (32 rows) x 2 groups. 256 thr = 4 waves.
// wave w = hc (col quarter): cols g*320 + 80*hc..+79 (5 cf), rows 0..31 (2 rf).
__global__ __launch_bounds__(256, 4) void vq_main(
    const float* __restrict__ H, const int* __restrict__ mask,
    const float* __restrict__ gumbel, const short* __restrict__ Wf,
    const float* __restrict__ bias, const float* __restrict__ cv,
    float* __restrict__ out, float* __restrict__ marg)
{
    __shared__ __align__(16) bf16x8 Alds[32][64];     // A tile, fragment-ordered, 32 KB
    __shared__ float red_s[128], red_z[128];
    __shared__ int   red_i[128];
    __shared__ float wrowS[32];
    __shared__ int   idxf[32];

    const int tid = threadIdx.x;
    const int l   = tid & 63, hc = tid >> 6;
    const int g   = blockIdx.x & 1;
    const int n0  = (blockIdx.x >> 1) * 32;
    const int q   = l >> 4,  ln = l & 15;
    const int ct0 = g * 20 + hc * 5;

    // ---- stage A tile: 2048 frag-lane slots / 256 threads = 8 each ----
#pragma unroll
    for (int i = 0; i < 8; ++i) {
        const int s  = tid + 256 * i;
        const int f  = s >> 6, sl = s & 63;
        const int rf = f >> 4, t = f & 15;
        const float* src = H + (size_t)(n0 + 16 * rf + (sl & 15)) * DD + 32 * t + 8 * (sl >> 4);
        float4 v0 = *(const float4*)src;
        float4 v1 = *(const float4*)(src + 4);
        Alds[f][sl] = pack8_rne(v0, v1);
    }
    __syncthreads();

    // ---- GEMM: B reg ping-pong pinned by sched_barrier, A from LDS ----
    f32x4 acc[2][5];
    const f32x4 vzero = {0.f, 0.f, 0.f, 0.f};
#pragma unroll
    for (int a = 0; a < 2; ++a)
#pragma unroll
        for (int b = 0; b < 5; ++b) acc[a][b] = vzero;

    const bf16x8* Wb8 = (const bf16x8*)Wf + l;   // + ((ct0+cf)*16+t)*64

    bf16x8 B0[5], B1[5], A0[2], A1[2];

#define LOADB(dst, t_)                                                         \
    { _Pragma("unroll")                                                        \
      for (int cf = 0; cf < 5; ++cf)                                           \
          dst[cf] = Wb8[(size_t)((ct0 + cf) * 16 + (t_)) * 64]; }
#define LOADA(dst, t_)                                                         \
    { dst[0] = Alds[(t_)][l]; dst[1] = Alds[16 + (t_)][l]; }
#define MFMA10(Ar, Br)                                                         \
    { __builtin_amdgcn_s_setprio(1);                                           \
      _Pragma("unroll")                                                        \
      for (int cf = 0; cf < 5; ++cf) {                                         \
          acc[0][cf] = __builtin_amdgcn_mfma_f32_16x16x32_bf16(Ar[0], Br[cf], acc[0][cf], 0, 0, 0); \
          acc[1][cf] = __builtin_amdgcn_mfma_f32_16x16x32_bf16(Ar[1], Br[cf], acc[1][cf], 0, 0, 0); } \
      __builtin_amdgcn_s_setprio(0); }

    LOADB(B0, 0) LOADA(A0, 0)
#pragma unroll 1
    for (int tt = 0; tt < 7; ++tt) {
        LOADB(B1, 2 * tt + 1) LOADA(A1, 2 * tt + 1)
        __builtin_amdgcn_sched_barrier(0);
        MFMA10(A0, B0)
        __builtin_amdgcn_sched_barrier(0);
        LOADB(B0, 2 * tt + 2) LOADA(A0, 2 * tt + 2)
        __builtin_amdgcn_sched_barrier(0);
        MFMA10(A1, B1)
        __builtin_amdgcn_sched_barrier(0);
    }
    LOADB(B1, 15) LOADA(A1, 15)
    __builtin_amdgcn_sched_barrier(0);
    MFMA10(A0, B0)
    __builtin_amdgcn_sched_barrier(0);
    MFMA10(A1, B1)

    // ---- batched epilogue loads: bias + all 40 gumbel values, then fence ----
    float bb[5];
#pragma unroll
    for (int cf = 0; cf < 5; ++cf) bb[cf] = bias[g * KK + hc * 80 + 16 * cf + ln];

    float gum[8][5];
#pragma unroll
    for (int rf = 0; rf < 2; ++rf)
#pragma unroll
        for (int reg = 0; reg < 4; ++reg) {
            const int row = 16 * rf + 4 * q + reg;
            const float* gp = gumbel + ((size_t)(n0 + row) * GG + g) * KK + hc * 80 + ln;
#pragma unroll
            for (int cf = 0; cf < 5; ++cf) gum[rf * 4 + reg][cf] = gp[16 * cf];
        }
    __builtin_amdgcn_sched_barrier(0);

    // ---- bias ----
#pragma unroll
    for (int cf = 0; cf < 5; ++cf)
#pragma unroll
        for (int rf = 0; rf < 2; ++rf) {
            acc[rf][cf][0] += bb[cf]; acc[rf][cf][1] += bb[cf];
            acc[rf][cf][2] += bb[cf]; acc[rf][cf][3] += bb[cf];
        }

    // ---- per-row stats, no-max softmax: {s, zm, zi} butterfly over 16 lanes ----
#pragma unroll
    for (int rf = 0; rf < 2; ++rf) {
#pragma unroll
        for (int reg = 0; reg < 4; ++reg) {
            const int row = 16 * rf + 4 * q + reg;
            float s = 0.f, zm = -3.0e38f;
            int zi = 0;
#pragma unroll
            for (int cf = 0; cf < 5; ++cf) {
                float v = acc[rf][cf][reg];
                s += __expf(v);
                float z = v + gum[rf * 4 + reg][cf];
                if (z > zm) { zm = z; zi = hc * 80 + 16 * cf + ln; }  // first-index tie rule
            }
#pragma unroll
            for (int d = 1; d <= 8; d <<= 1) {
                s += __shfl_xor(s, d);
                float zo = __shfl_xor(zm, d);
                int   io = __shfl_xor(zi, d);
                if (zo > zm || (zo == zm && io < zi)) { zm = zo; zi = io; }
            }
            if (ln == 0) {
                const int base = row * 4 + hc;
                red_s[base] = s;
                red_z[base] = zm; red_i[base] = zi;
            }
        }
    }
    __syncthreads();

    // ---- combine 4 col-quarters per row ----
    if (tid < 32) {
        const int b0 = tid * 4;
        float Z = red_s[b0] + red_s[b0 + 1] + red_s[b0 + 2] + red_s[b0 + 3];
        float zb = -3.0e38f; int ib = 0;
#pragma unroll
        for (int h = 0; h < 4; ++h)
            if (red_z[b0 + h] > zb) { zb = red_z[b0 + h]; ib = red_i[b0 + h]; }  // ascending h: first max wins
        idxf[tid]  = ib;
        wrowS[tid] = ((mask[n0 + tid] != 0) ? 1.0f : 0.0f) / Z;
    }
    __syncthreads();

    // ---- marginal: per-col partials over this block's 32 rows ----
    float cs[5] = {0.f, 0.f, 0.f, 0.f, 0.f};
#pragma unroll
    for (int rf = 0; rf < 2; ++rf) {
#pragma unroll
        for (int reg = 0; reg < 4; ++reg) {
            const int row = 16 * rf + 4 * q + reg;
            const float wv = wrowS[row];
#pragma unroll
            for (int cf = 0; cf < 5; ++cf)
                cs[cf] += __expf(acc[rf][cf][reg]) * wv;
        }
    }
    {
        float* mc = marg + (size_t)(blockIdx.x & (NCPY - 1)) * (GG * KK);
#pragma unroll
        for (int cf = 0; cf < 5; ++cf) {
            float v = cs[cf];
            v += __shfl_xor(v, 16);
            v += __shfl_xor(v, 32);
            if (l < 16) atomicAdd(&mc[g * KK + hc * 80 + 16 * cf + l], v);
        }
    }

    // ---- codevector gather (float4): this block writes its group's 128-half ----
#pragma unroll
    for (int i = 0; i < 4; ++i) {
        const int e = tid + 256 * i;                 // 1024 float4 slots
        const int row = e >> 5, d4 = e & 31;
        const float4 val = ((const float4*)(cv + ((size_t)g * KK + idxf[row]) * DPG))[d4];
        ((float4*)(out + (size_t)(n0 + row) * 256 + g * DPG))[d4] = val;
    }
}

// ---------- perplexity finalize ----------
__global__ __launch_bounds__(256) void finalize_kernel(
    const int* __restrict__ mask, const float* __restrict__ marg,
    float* __restrict__ perp_out)
{
    __shared__ float red[256];
    __shared__ float hg[GG];
    const int tid = threadIdx.x;

    int cnt = 0;
    for (int n = tid; n < NN; n += 256) cnt += (mask[n] != 0) ? 1 : 0;
    red[tid] = (float)cnt;
    __syncthreads();
    for (int s = 128; s > 0; s >>= 1) {
        if (tid < s) red[tid] += red[tid + s];
        __syncthreads();
    }
    const float invc = 1.0f / red[0];
    __syncthreads();

    for (int g = 0; g < GG; ++g) {
        float h = 0.0f;
        for (int c = tid; c < KK; c += 256) {
            float m = 0.f;
#pragma unroll
            for (int x = 0; x < NCPY; ++x) m += marg[x * (GG * KK) + g * KK + c];
            m *= invc;
            h += m * logf(m + EPSL);
        }
        red[tid] = h;
        __syncthreads();
        for (int s = 128; s > 0; s >>= 1) {
            if (tid < s) red[tid] += red[tid + s];
            __syncthreads();
        }
        if (tid == 0) hg[g] = red[0];
        __syncthreads();
    }
    if (tid == 0) perp_out[0] = expf(-hg[0]) + expf(-hg[1]);
}

extern "C" void kernel_launch(void* const* d_in, const int* in_sizes, int n_in,
                              void* d_out, int out_size, void* d_ws, size_t ws_size,
                              hipStream_t stream)
{
    const float* H      = (const float*)d_in[0];   // (32,2048,512) f32
    const int*   mask   = (const int*)d_in[1];     // (32,2048) bool->int32
    const float* gumbel = (const float*)d_in[2];   // (131072,320) f32
    const float* W      = (const float*)d_in[3];   // (640,512) f32
    const float* bias   = (const float*)d_in[4];   // (640,) f32
    const float* cv     = (const float*)d_in[5];   // (1,640,128) f32

    float*  out  = (float*)d_out;                  // 16777216 + 1 floats
    float*  marg = (float*)d_ws;                   // 8 copies x 640 f32
    short*  Wf   = (short*)((char*)d_ws + 32768);  // 0.66 MB bf16 frags

    hipMemsetAsync(marg, 0, NCPY * GG * KK * sizeof(float), stream);
    prep_w<<<160, 256, 0, stream>>>(W, Wf);
    vq_main<<<4096, 256, 0, stream>>>(H, mask, gumbel, Wf, bias, cv, out, marg);
    finalize_kernel<<<1, 256, 0, stream>>>(mask, marg, out + (size_t)NN * GG * DPG);
}

// Round 11
// 183.069 us; speedup vs baseline: 1.0226x; 1.0226x over previous
//
#include <hip/hip_runtime.h>

// Wav2Vec2 Gumbel VQ — round 11: r10 geometry + DEPTH-3 software pipeline.
// At cluster t, issue B(L2)/A(LDS) loads for t+2 (sched_barrier-pinned, fully
// unrolled so all buffer indices are static). load->use ~= 2 clusters ~= L2
// latency. launch_bounds(256,3) -> ~168 VGPR cap, 3 blocks/CU.

#define GG   2
#define KK   320
#define NN   65536
#define DD   512
#define DPG  128
#define EPSL 1e-7f
#define NCPY 8

typedef __attribute__((ext_vector_type(8))) short bf16x8;   // 8 x bf16
typedef __attribute__((ext_vector_type(4))) float f32x4;

static __device__ __forceinline__ unsigned short f2bf_rne(float f) {
    unsigned u = __float_as_uint(f);
    u += 0x7FFFu + ((u >> 16) & 1u);
    return (unsigned short)(u >> 16);
}

static __device__ __forceinline__ bf16x8 pack8_rne(float4 v0, float4 v1) {
    union { unsigned short s[8]; bf16x8 b; } u;
    u.s[0] = f2bf_rne(v0.x); u.s[1] = f2bf_rne(v0.y);
    u.s[2] = f2bf_rne(v0.z); u.s[3] = f2bf_rne(v0.w);
    u.s[4] = f2bf_rne(v1.x); u.s[5] = f2bf_rne(v1.y);
    u.s[6] = f2bf_rne(v1.z); u.s[7] = f2bf_rne(v1.w);
    return u.b;
}

// ---------- prep: W (640x512 f32) -> fragment-ordered bf16 (RNE) ----------
// w = ct*16 + t; element (w*512 + l*8 + j) = W[col=16ct+(l&15)][k=32t+8(l>>4)+j]
__global__ __launch_bounds__(256) void prep_w(const float* __restrict__ W,
                                              short* __restrict__ Wf) {
    int gt = blockIdx.x * 256 + threadIdx.x;          // 40960 threads
    int w  = gt >> 6, l = gt & 63;
    int col = 16 * (w >> 4) + (l & 15);
    int k0  = 32 * (w & 15) + 8 * (l >> 4);
    const float* src = W + (size_t)col * DD + k0;
    float4 v0 = *(const float4*)(src);
    float4 v1 = *(const float4*)(src + 4);
    *(bf16x8*)(Wf + (size_t)w * 512 + (size_t)l * 8) = pack8_rne(v0, v1);
}

// ---------- main fused kernel ----------
// grid: 4096 blocks = 2048 row-tiles (32 rows) x 2 groups. 256 thr = 4 waves.
// wave hc (col quarter): cols g*320 + 80*hc..+79 (5 cf), rows 0..31 (2 rf).
__global__ __launch_bounds__(256, 3) void vq_main(
    const float* __restrict__ H, const int* __restrict__ mask,
    const float* __restrict__ gumbel, const short* __restrict__ Wf,
    const float* __restrict__ bias, const float* __restrict__ cv,
    float* __restrict__ out, float* __restrict__ marg)
{
    __shared__ __align__(16) bf16x8 Alds[32][64];     // A tile, fragment-ordered, 32 KB
    __shared__ float red_s[128], red_z[128];
    __shared__ int   red_i[128];
    __shared__ float wrowS[32];
    __shared__ int   idxf[32];

    const int tid = threadIdx.x;
    const int l   = tid & 63, hc = tid >> 6;
    const int g   = blockIdx.x & 1;
    const int n0  = (blockIdx.x >> 1) * 32;
    const int q   = l >> 4,  ln = l & 15;
    const int ct0 = g * 20 + hc * 5;

    // ---- stage A tile: 2048 frag-lane slots / 256 threads = 8 each ----
#pragma unroll
    for (int i = 0; i < 8; ++i) {
        const int s  = tid + 256 * i;
        const int f  = s >> 6, sl = s & 63;
        const int rf = f >> 4, t = f & 15;
        const float* src = H + (size_t)(n0 + 16 * rf + (sl & 15)) * DD + 32 * t + 8 * (sl >> 4);
        float4 v0 = *(const float4*)src;
        float4 v1 = *(const float4*)(src + 4);
        Alds[f][sl] = pack8_rne(v0, v1);
    }
    __syncthreads();

    // ---- GEMM: depth-3 pipelined, fully unrolled, sched_barrier-pinned ----
    f32x4 acc[2][5];
    const f32x4 vzero = {0.f, 0.f, 0.f, 0.f};
#pragma unroll
    for (int a = 0; a < 2; ++a)
#pragma unroll
        for (int b = 0; b < 5; ++b) acc[a][b] = vzero;

    const bf16x8* Wb8 = (const bf16x8*)Wf + l;   // + ((ct0+cf)*16+t)*64

    bf16x8 B[3][5], A[3][2];

#define LOADB(bi, t_)                                                          \
    { _Pragma("unroll")                                                        \
      for (int cf = 0; cf < 5; ++cf)                                           \
          B[bi][cf] = Wb8[(size_t)((ct0 + cf) * 16 + (t_)) * 64]; }
#define LOADA(bi, t_)                                                          \
    { A[bi][0] = Alds[(t_)][l]; A[bi][1] = Alds[16 + (t_)][l]; }
#define MFMA10(bi)                                                             \
    { __builtin_amdgcn_s_setprio(1);                                           \
      _Pragma("unroll")                                                        \
      for (int cf = 0; cf < 5; ++cf) {                                         \
          acc[0][cf] = __builtin_amdgcn_mfma_f32_16x16x32_bf16(A[bi][0], B[bi][cf], acc[0][cf], 0, 0, 0); \
          acc[1][cf] = __builtin_amdgcn_mfma_f32_16x16x32_bf16(A[bi][1], B[bi][cf], acc[1][cf], 0, 0, 0); } \
      __builtin_amdgcn_s_setprio(0); }

    LOADB(0, 0) LOADA(0, 0)
    LOADB(1, 1) LOADA(1, 1)
    __builtin_amdgcn_sched_barrier(0);
#pragma unroll
    for (int t = 0; t < 16; ++t) {
        if (t + 2 < 16) {
            LOADB((t + 2) % 3, t + 2)
            LOADA((t + 2) % 3, t + 2)
        }
        __builtin_amdgcn_sched_barrier(0);
        MFMA10(t % 3)
        __builtin_amdgcn_sched_barrier(0);
    }

    // ---- batched epilogue loads: bias + all 40 gumbel values, then fence ----
    float bb[5];
#pragma unroll
    for (int cf = 0; cf < 5; ++cf) bb[cf] = bias[g * KK + hc * 80 + 16 * cf + ln];

    float gum[8][5];
#pragma unroll
    for (int rf = 0; rf < 2; ++rf)
#pragma unroll
        for (int reg = 0; reg < 4; ++reg) {
            const int row = 16 * rf + 4 * q + reg;
            const float* gp = gumbel + ((size_t)(n0 + row) * GG + g) * KK + hc * 80 + ln;
#pragma unroll
            for (int cf = 0; cf < 5; ++cf) gum[rf * 4 + reg][cf] = gp[16 * cf];
        }
    __builtin_amdgcn_sched_barrier(0);

    // ---- bias ----
#pragma unroll
    for (int cf = 0; cf < 5; ++cf)
#pragma unroll
        for (int rf = 0; rf < 2; ++rf) {
            acc[rf][cf][0] += bb[cf]; acc[rf][cf][1] += bb[cf];
            acc[rf][cf][2] += bb[cf]; acc[rf][cf][3] += bb[cf];
        }

    // ---- per-row stats, no-max softmax: {s, zm, zi} butterfly over 16 lanes ----
#pragma unroll
    for (int rf = 0; rf < 2; ++rf) {
#pragma unroll
        for (int reg = 0; reg < 4; ++reg) {
            const int row = 16 * rf + 4 * q + reg;
            float s = 0.f, zm = -3.0e38f;
            int zi = 0;
#pragma unroll
            for (int cf = 0; cf < 5; ++cf) {
                float v = acc[rf][cf][reg];
                s += __expf(v);
                float z = v + gum[rf * 4 + reg][cf];
                if (z > zm) { zm = z; zi = hc * 80 + 16 * cf + ln; }  // first-index tie rule
            }
#pragma unroll
            for (int d = 1; d <= 8; d <<= 1) {
                s += __shfl_xor(s, d);
                float zo = __shfl_xor(zm, d);
                int   io = __shfl_xor(zi, d);
                if (zo > zm || (zo == zm && io < zi)) { zm = zo; zi = io; }
            }
            if (ln == 0) {
                const int base = row * 4 + hc;
                red_s[base] = s;
                red_z[base] = zm; red_i[base] = zi;
            }
        }
    }
    __syncthreads();

    // ---- combine 4 col-quarters per row ----
    if (tid < 32) {
        const int b0 = tid * 4;
        float Z = red_s[b0] + red_s[b0 + 1] + red_s[b0 + 2] + red_s[b0 + 3];
        float zb = -3.0e38f; int ib = 0;
#pragma unroll
        for (int h = 0; h < 4; ++h)
            if (red_z[b0 + h] > zb) { zb = red_z[b0 + h]; ib = red_i[b0 + h]; }  // ascending h: first max wins
        idxf[tid]  = ib;
        wrowS[tid] = ((mask[n0 + tid] != 0) ? 1.0f : 0.0f) / Z;
    }
    __syncthreads();

    // ---- marginal: per-col partials over this block's 32 rows ----
    float cs[5] = {0.f, 0.f, 0.f, 0.f, 0.f};
#pragma unroll
    for (int rf = 0; rf < 2; ++rf) {
#pragma unroll
        for (int reg = 0; reg < 4; ++reg) {
            const int row = 16 * rf + 4 * q + reg;
            const float wv = wrowS[row];
#pragma unroll
            for (int cf = 0; cf < 5; ++cf)
                cs[cf] += __expf(acc[rf][cf][reg]) * wv;
        }
    }
    {
        float* mc = marg + (size_t)(blockIdx.x & (NCPY - 1)) * (GG * KK);
#pragma unroll
        for (int cf = 0; cf < 5; ++cf) {
            float v = cs[cf];
            v += __shfl_xor(v, 16);
            v += __shfl_xor(v, 32);
            if (l < 16) atomicAdd(&mc[g * KK + hc * 80 + 16 * cf + l], v);
        }
    }

    // ---- codevector gather (float4): this block writes its group's 128-half ----
#pragma unroll
    for (int i = 0; i < 4; ++i) {
        const int e = tid + 256 * i;                 // 1024 float4 slots
        const int row = e >> 5, d4 = e & 31;
        const float4 val = ((const float4*)(cv + ((size_t)g * KK + idxf[row]) * DPG))[d4];
        ((float4*)(out + (size_t)(n0 + row) * 256 + g * DPG))[d4] = val;
    }
}

// ---------- perplexity finalize ----------
__global__ __launch_bounds__(256) void finalize_kernel(
    const int* __restrict__ mask, const float* __restrict__ marg,
    float* __restrict__ perp_out)
{
    __shared__ float red[256];
    __shared__ float hg[GG];
    const int tid = threadIdx.x;

    int cnt = 0;
    for (int n = tid; n < NN; n += 256) cnt += (mask[n] != 0) ? 1 : 0;
    red[tid] = (float)cnt;
    __syncthreads();
    for (int s = 128; s > 0; s >>= 1) {
        if (tid < s) red[tid] += red[tid + s];
        __syncthreads();
    }
    const float invc = 1.0f / red[0];
    __syncthreads();

    for (int g = 0; g < GG; ++g) {
        float h = 0.0f;
        for (int c = tid; c < KK; c += 256) {
            float m = 0.f;
#pragma unroll
            for (int x = 0; x < NCPY; ++x) m += marg[x * (GG * KK) + g * KK + c];
            m *= invc;
            h += m * logf(m + EPSL);
        }
        red[tid] = h;
        __syncthreads();
        for (int s = 128; s > 0; s >>= 1) {
            if (tid < s) red[tid] += red[tid + s];
            __syncthreads();
        }
        if (tid == 0) hg[g] = red[0];
        __syncthreads();
    }
    if (tid == 0) perp_out[0] = expf(-hg[0]) + expf(-hg[1]);
}

extern "C" void kernel_launch(void* const* d_in, const int* in_sizes, int n_in,
                              void* d_out, int out_size, void* d_ws, size_t ws_size,
                              hipStream_t stream)
{
    const float* H      = (const float*)d_in[0];   // (32,2048,512) f32
    const int*   mask   = (const int*)d_in[1];     // (32,2048) bool->int32
    const float* gumbel = (const float*)d_in[2];   // (131072,320) f32
    const float* W      = (const float*)d_in[3];   // (640,512) f32
    const float* bias   = (const float*)d_in[4];   // (640,) f32
    const float* cv     = (const float*)d_in[5];   // (1,640,128) f32

    float*  out  = (float*)d_out;                  // 16777216 + 1 floats
    float*  marg = (float*)d_ws;                   // 8 copies x 640 f32
    short*  Wf   = (short*)((char*)d_ws + 32768);  // 0.66 MB bf16 frags

    hipMemsetAsync(marg, 0, NCPY * GG * KK * sizeof(float), stream);
    prep_w<<<160, 256, 0, stream>>>(W, Wf);
    vq_main<<<4096, 256, 0, stream>>>(H, mask, gumbel, Wf, bias, cv, out, marg);
    finalize_kernel<<<1, 256, 0, stream>>>(mask, marg, out + (size_t)NN * GG * DPG);
}